// Round 5
// baseline (5225.695 us; speedup 1.0000x reference)
//
#include <hip/hip_runtime.h>
#include <hip/hip_bf16.h>
#include <hip/hip_cooperative_groups.h>
#include <cstdint>
#include <cstddef>

namespace cg = cooperative_groups;

// Problem dims
#define B_    256
#define T_    64
#define H_    512
#define DIN_  2048
#define BT_   (B_ * T_)     // 16384
#define NPRE_ 2560          // [i_r, i_i, i_n, t1, t2] columns
#define NCAT_ 2048          // [h_r, h_i, h_n, q~] columns
#define NV_   2048          // [Vt1|Vir|Vt2|Vii] columns

typedef __attribute__((ext_vector_type(8))) __bf16 bf16x8;
typedef __attribute__((ext_vector_type(4))) float  f32x4;

__device__ __forceinline__ float bf2f(unsigned short u) {
    union { unsigned int i; float f; } v; v.i = ((unsigned int)u) << 16; return v.f;
}
__device__ __forceinline__ unsigned short f2bf(float f) {
    union { float f; unsigned int i; } v; v.f = f;
    unsigned int x = v.i;
    return (unsigned short)((x + 0x7fffu + ((x >> 16) & 1u)) >> 16);
}

// async global->LDS, 16B per lane. LDS dest must be wave-uniform base + lane*16
// (tid-linear dest satisfies this: readfirstlane(base)+lane*16 == tid*16).
__device__ __forceinline__ void gload_lds16(const unsigned short* g, unsigned short* l) {
    __builtin_amdgcn_global_load_lds(
        (const __attribute__((address_space(1))) void*)g,
        (__attribute__((address_space(3))) void*)l, 16, 0, 0);
}

// ---------------- cast fp32 -> bf16, 4 elems/thread ----------------
__global__ void cast4_kernel(const float* __restrict__ src,
                             unsigned short* __restrict__ dst, int n4) {
    int i = blockIdx.x * blockDim.x + threadIdx.x;
    if (i >= n4) return;
    const float4 v = ((const float4*)src)[i];
    ushort4 o;
    o.x = f2bf(v.x); o.y = f2bf(v.y); o.z = f2bf(v.z); o.w = f2bf(v.w);
    ((ushort4*)dst)[i] = o;
}

// ---------------- Wqk = Wk^T @ Wq (fp32 in, bf16 out) ----------------
// Wqk[j,h] = sum_o Wk[o,j] * Wq[o,h]; output written to Wcat rows 1536..2047
__global__ __launch_bounds__(256)
void wqk_kernel(const float* __restrict__ Wk, const float* __restrict__ Wq,
                unsigned short* __restrict__ Wout) {
    __shared__ float sk[16][17], sq[16][17];
    const int tid = threadIdx.x;
    const int tx = tid & 15, ty = tid >> 4;
    const int j0 = blockIdx.y * 16, h0 = blockIdx.x * 16;
    float acc = 0.f;
    for (int o0 = 0; o0 < 512; o0 += 16) {
        sk[ty][tx] = Wk[(o0 + ty) * 512 + j0 + tx];
        sq[ty][tx] = Wq[(o0 + ty) * 512 + h0 + tx];
        __syncthreads();
        #pragma unroll
        for (int oo = 0; oo < 16; oo++)
            acc = fmaf(sk[oo][ty], sq[oo][tx], acc);
        __syncthreads();
    }
    Wout[(size_t)(j0 + ty) * 512 + h0 + tx] = f2bf(acc);
}

// bqk[j] = sum_o Wk[o,j] * bq[o]
__global__ void bqk_kernel(const float* __restrict__ Wk, const float* __restrict__ bq,
                           float* __restrict__ bout) {
    int j = blockIdx.x * 64 + threadIdx.x;
    float acc = 0.f;
    for (int o = 0; o < 512; o++)
        acc = fmaf(Wk[o * 512 + j], bq[o], acc);
    bout[j] = acc;
}

// ---------------- bf16 GEMM (m97 LDS-staged variant, throughput path) ----------------
// 128x128 tile, BK=32, global_load_lds width=16 into linear [128][32] LDS (8KB each),
// ds_read_b128 fragments, 16 MFMA/wave/K-step, 2 barriers per K-step.
// Epilogue also writes a PACKED bf16 mirror Apk[16384][2048] = [t1|ir|t2|ii].
__global__ __launch_bounds__(256)
void gemm_lds(const unsigned short* __restrict__ A0,
              const unsigned short* __restrict__ A1, int nsplit,
              const unsigned short* __restrict__ W,
              const float* __restrict__ bias,
              float* __restrict__ C,
              unsigned short* __restrict__ Apk, int N, int K) {
    __shared__ unsigned short sA[128 * 32];   // [128][32] row-major, 64B/row
    __shared__ unsigned short sB[128 * 32];
    const int n0 = blockIdx.x * 128;
    const int m0 = blockIdx.y * 128;
    const unsigned short* A = (n0 < nsplit) ? A0 : A1;
    const int tid = threadIdx.x;
    const int wave = tid >> 6, lane = tid & 63;
    const int wm = (wave >> 1) * 64, wn = (wave & 1) * 64;
    const int row16 = lane & 15;
    const int kq = (lane >> 4) * 8;

    f32x4 acc[4][4];
    #pragma unroll
    for (int i = 0; i < 4; i++)
        #pragma unroll
        for (int j = 0; j < 4; j++) {
            acc[i][j].x = 0.f; acc[i][j].y = 0.f; acc[i][j].z = 0.f; acc[i][j].w = 0.f;
        }

    const int srow = tid >> 2;
    const int scol = (tid & 3) * 8;
    const unsigned short* gA0 = A + (size_t)(m0 + srow) * K + scol;
    const unsigned short* gA1 = A + (size_t)(m0 + 64 + srow) * K + scol;
    const unsigned short* gB0 = W + (size_t)(n0 + srow) * K + scol;
    const unsigned short* gB1 = W + (size_t)(n0 + 64 + srow) * K + scol;
    unsigned short* dA0 = sA + tid * 8;
    unsigned short* dA1 = sA + 2048 + tid * 8;
    unsigned short* dB0 = sB + tid * 8;
    unsigned short* dB1 = sB + 2048 + tid * 8;

    for (int k = 0; k < K; k += 32) {
        gload_lds16(gA0 + k, dA0);
        gload_lds16(gA1 + k, dA1);
        gload_lds16(gB0 + k, dB0);
        gload_lds16(gB1 + k, dB1);
        __syncthreads();   // compiler drains vmcnt before s_barrier
        bf16x8 a[4], b[4];
        #pragma unroll
        for (int i = 0; i < 4; i++)
            a[i] = *(const bf16x8*)(const void*)(sA + (wm + i * 16 + row16) * 32 + kq);
        #pragma unroll
        for (int j = 0; j < 4; j++)
            b[j] = *(const bf16x8*)(const void*)(sB + (wn + j * 16 + row16) * 32 + kq);
        #pragma unroll
        for (int i = 0; i < 4; i++)
            #pragma unroll
            for (int j = 0; j < 4; j++)
                acc[i][j] = __builtin_amdgcn_mfma_f32_16x16x32_bf16(a[i], b[j], acc[i][j], 0, 0, 0);
        __syncthreads();   // protect LDS before next stage
    }

    // packed-column base for the Apk mirror (whole 128-col tile maps uniformly)
    int pbase = -1;
    if (n0 >= 1536 && n0 < 2048)      pbase = n0 - 1536;  // t1 -> [0,512)
    else if (n0 < 512)                pbase = n0 + 512;   // i_r -> [512,1024)
    else if (n0 >= 2048)              pbase = n0 - 1024;  // t2 -> [1024,1536)
    else if (n0 >= 512 && n0 < 1024)  pbase = n0 + 1024;  // i_i -> [1536,2048)
    // n0 in [1024,1536) = i_n -> no mirror

    const int col = lane & 15;
    const int rbase = (lane >> 4) * 4;
    #pragma unroll
    for (int i = 0; i < 4; i++) {
        #pragma unroll
        for (int j = 0; j < 4; j++) {
            const int nloc = wn + j * 16 + col;
            const int n = n0 + nloc;
            const float bb = bias[n];
            #pragma unroll
            for (int r = 0; r < 4; r++) {
                const int m = m0 + wm + i * 16 + rbase + r;
                const float val = acc[i][j][r] + bb;
                C[(size_t)m * N + n] = val;
                if (pbase >= 0)
                    Apk[(size_t)m * NV_ + pbase + nloc] = f2bf(val);
            }
        }
    }
}

// ---------------- V pre-GEMM: Vbf[m, g*512+n'] = sum_k Apk[m, g*512+k]*Wv[n',k] + bv[n'] ----------------
__global__ __launch_bounds__(256)
void gemm_v(const unsigned short* __restrict__ Apk,   // [16384][2048] bf16
            const unsigned short* __restrict__ Wvbf,  // [512][512] bf16 (Wv[o,h], k=h)
            const float* __restrict__ bv,
            unsigned short* __restrict__ Vbf) {       // [16384][2048] bf16
    __shared__ unsigned short sA[128 * 32];
    __shared__ unsigned short sB[128 * 32];
    const int n0 = blockIdx.x * 128;     // 0..1920
    const int m0 = blockIdx.y * 128;
    const int aoff = n0 & ~511;          // column-group base in Apk
    const int nb0 = n0 & 511;            // row base in Wvbf
    const int tid = threadIdx.x;
    const int wave = tid >> 6, lane = tid & 63;
    const int wm = (wave >> 1) * 64, wn = (wave & 1) * 64;
    const int row16 = lane & 15;
    const int kq = (lane >> 4) * 8;

    f32x4 acc[4][4];
    #pragma unroll
    for (int i = 0; i < 4; i++)
        #pragma unroll
        for (int j = 0; j < 4; j++) {
            acc[i][j].x = 0.f; acc[i][j].y = 0.f; acc[i][j].z = 0.f; acc[i][j].w = 0.f;
        }

    const int srow = tid >> 2;
    const int scol = (tid & 3) * 8;
    const unsigned short* gA0 = Apk + (size_t)(m0 + srow) * NV_ + aoff + scol;
    const unsigned short* gA1 = Apk + (size_t)(m0 + 64 + srow) * NV_ + aoff + scol;
    const unsigned short* gB0 = Wvbf + (size_t)(nb0 + srow) * 512 + scol;
    const unsigned short* gB1 = Wvbf + (size_t)(nb0 + 64 + srow) * 512 + scol;
    unsigned short* dA0 = sA + tid * 8;
    unsigned short* dA1 = sA + 2048 + tid * 8;
    unsigned short* dB0 = sB + tid * 8;
    unsigned short* dB1 = sB + 2048 + tid * 8;

    for (int k = 0; k < 512; k += 32) {
        gload_lds16(gA0 + k, dA0);
        gload_lds16(gA1 + k, dA1);
        gload_lds16(gB0 + k, dB0);
        gload_lds16(gB1 + k, dB1);
        __syncthreads();
        bf16x8 a[4], b[4];
        #pragma unroll
        for (int i = 0; i < 4; i++)
            a[i] = *(const bf16x8*)(const void*)(sA + (wm + i * 16 + row16) * 32 + kq);
        #pragma unroll
        for (int j = 0; j < 4; j++)
            b[j] = *(const bf16x8*)(const void*)(sB + (wn + j * 16 + row16) * 32 + kq);
        #pragma unroll
        for (int i = 0; i < 4; i++)
            #pragma unroll
            for (int j = 0; j < 4; j++)
                acc[i][j] = __builtin_amdgcn_mfma_f32_16x16x32_bf16(a[i], b[j], acc[i][j], 0, 0, 0);
        __syncthreads();
    }

    const int col = lane & 15;
    const int rbase = (lane >> 4) * 4;
    #pragma unroll
    for (int i = 0; i < 4; i++) {
        #pragma unroll
        for (int j = 0; j < 4; j++) {
            const int nloc = wn + j * 16 + col;
            const float bb = bv[nb0 + nloc];
            #pragma unroll
            for (int r = 0; r < 4; r++) {
                const int m = m0 + wm + i * 16 + rbase + r;
                Vbf[(size_t)m * NV_ + n0 + nloc] = f2bf(acc[i][j][r] + bb);
            }
        }
    }
}

// ---------------- persistent cooperative recurrence kernel ----------------
// 256 blocks x 256 threads, loops t=0..63 internally.
// Phase 1: comb = hxbf @ Wcat^T + bcat. Block (mt,nt)=(bid>>5, bid&31) owns a
//   32x64 tile; 4 waves, wave tile 16x32 (2 MFMAs/K-iter), direct loads.
// Phase 2: block b = bid does attention+gates for batch row b (2 h per thread);
//   hx carried in registers (hy0/hy1) across t.
// grid.sync() between phases provides cross-XCD visibility (device-scope fence).
__global__ __launch_bounds__(256)
void loop_kernel(unsigned short* __restrict__ hxbf,      // [256,512] bf16, init 0
                 const unsigned short* __restrict__ Wcat,// [2048,512] bf16
                 const float* __restrict__ bcat,         // [2048]
                 float* __restrict__ comb,               // [256,2048] fp32 scratch
                 const float* __restrict__ Cpre,         // [16384,2560]
                 const unsigned short* __restrict__ Vbf, // [16384,2048]
                 float* __restrict__ out) {
    cg::grid_group grid = cg::this_grid();
    const int bid = blockIdx.x;
    const int tid = threadIdx.x;
    const int wave = tid >> 6, lane = tid & 63;

    // phase-1 tile geometry
    const int m0 = (bid >> 5) * 32, n0 = (bid & 31) * 64;
    const int wr = wave & 1, wc = wave >> 1;
    const int row16 = lane & 15, kq = (lane >> 4) * 8;
    const int col = lane & 15, rbase = (lane >> 4) * 4;
    const unsigned short* abase = hxbf + (size_t)(m0 + wr * 16 + row16) * H_ + kq;
    const unsigned short* bbase = Wcat + (size_t)(n0 + wc * 32 + row16) * H_ + kq;
    const int nc0 = n0 + wc * 32 + col;          // output col of acc0; acc1 at +16
    const float bb0 = bcat[nc0], bb1 = bcat[nc0 + 16];

    // phase-2 state
    const int b = bid;
    const int h0 = tid, h1 = tid + 256;
    float hy0 = 0.f, hy1 = 0.f;
    __shared__ float red[4][4];
    const float scale = 0.04419417382415922f; // 1/sqrt(512)

    for (int t = 0; t < T_; t++) {
        // ---- phase 1: GEMM tile
        f32x4 acc0 = {0.f, 0.f, 0.f, 0.f}, acc1 = {0.f, 0.f, 0.f, 0.f};
        #pragma unroll 4
        for (int k = 0; k < H_; k += 32) {
            bf16x8 av  = *(const bf16x8*)(const void*)(abase + k);
            bf16x8 b0v = *(const bf16x8*)(const void*)(bbase + k);
            bf16x8 b1v = *(const bf16x8*)(const void*)(bbase + (size_t)16 * H_ + k);
            acc0 = __builtin_amdgcn_mfma_f32_16x16x32_bf16(av, b0v, acc0, 0, 0, 0);
            acc1 = __builtin_amdgcn_mfma_f32_16x16x32_bf16(av, b1v, acc1, 0, 0, 0);
        }
        #pragma unroll
        for (int r = 0; r < 4; r++) {
            const int m = m0 + wr * 16 + rbase + r;
            comb[(size_t)m * NCAT_ + nc0]      = acc0[r] + bb0;
            comb[(size_t)m * NCAT_ + nc0 + 16] = acc1[r] + bb1;
        }
        grid.sync();   // comb visible to all blocks

        // ---- phase 2: attention + gates for batch row b
        const float* combRow = comb + (size_t)b * NCAT_;
        const float* pre = Cpre + (size_t)(b * T_ + t) * NPRE_;
        const unsigned short* vrow = Vbf + (size_t)(b * T_ + t) * NV_;

        const float q0  = combRow[1536 + h0], q1  = combRow[1536 + h1];
        const float t1a = pre[1536 + h0],     t1b = pre[1536 + h1];
        const float ira = pre[h0],            irb = pre[h1];
        const float t2a = pre[2048 + h0],     t2b = pre[2048 + h1];
        const float iia = pre[512 + h0],      iib = pre[512 + h1];

        float pr0 = q0 * t1a + q1 * t1b;
        float pr1 = q0 * ira + q1 * irb;
        float pi0 = q0 * t2a + q1 * t2b;
        float pi1 = q0 * iia + q1 * iib;
        #pragma unroll
        for (int off = 32; off > 0; off >>= 1) {
            pr0 += __shfl_down(pr0, off);
            pr1 += __shfl_down(pr1, off);
            pi0 += __shfl_down(pi0, off);
            pi1 += __shfl_down(pi1, off);
        }
        if (lane == 0) {
            red[wave][0] = pr0; red[wave][1] = pr1;
            red[wave][2] = pi0; red[wave][3] = pi1;
        }
        __syncthreads();
        const float s_r0 = red[0][0] + red[1][0] + red[2][0] + red[3][0];
        const float s_r1 = red[0][1] + red[1][1] + red[2][1] + red[3][1];
        const float s_i0 = red[0][2] + red[1][2] + red[2][2] + red[3][2];
        const float s_i1 = red[0][3] + red[1][3] + red[2][3] + red[3][3];
        const float prob_r0 = 1.f / (1.f + expf((s_r1 - s_r0) * scale));
        const float prob_i0 = 1.f / (1.f + expf((s_i1 - s_i0) * scale));

        {   // h0
            const float cr = prob_r0 * bf2f(vrow[h0]) + (1.f - prob_r0) * bf2f(vrow[512 + h0]);
            const float ci = prob_i0 * bf2f(vrow[1024 + h0]) + (1.f - prob_i0) * bf2f(vrow[1536 + h0]);
            const float rg = 1.f / (1.f + expf(-(cr + combRow[h0])));
            const float ig = 1.f / (1.f + expf(-(ci + combRow[512 + h0])));
            const float ng = tanhf(fmaf(rg, combRow[1024 + h0], pre[1024 + h0]));
            hy0 = ng + ig * (hy0 - ng);
            out[(size_t)(b * T_ + t) * H_ + h0] = hy0;
            hxbf[(size_t)b * H_ + h0] = f2bf(hy0);
        }
        {   // h1
            const float cr = prob_r0 * bf2f(vrow[h1]) + (1.f - prob_r0) * bf2f(vrow[512 + h1]);
            const float ci = prob_i0 * bf2f(vrow[1024 + h1]) + (1.f - prob_i0) * bf2f(vrow[1536 + h1]);
            const float rg = 1.f / (1.f + expf(-(cr + combRow[h1])));
            const float ig = 1.f / (1.f + expf(-(ci + combRow[512 + h1])));
            const float ng = tanhf(fmaf(rg, combRow[1024 + h1], pre[1024 + h1]));
            hy1 = ng + ig * (hy1 - ng);
            out[(size_t)(b * T_ + t) * H_ + h1] = hy1;
            hxbf[(size_t)b * H_ + h1] = f2bf(hy1);
        }
        if (t == T_ - 1) {
            out[(size_t)B_ * T_ * H_ + (size_t)b * H_ + h0] = hy0;
            out[(size_t)B_ * T_ * H_ + (size_t)b * H_ + h1] = hy1;
        }
        grid.sync();   // hxbf visible before next phase 1
    }
}

extern "C" void kernel_launch(void* const* d_in, const int* in_sizes, int n_in,
                              void* d_out, int out_size, void* d_ws, size_t ws_size,
                              hipStream_t stream) {
    const float* input_feats = (const float*)d_in[0];
    const float* aux0   = (const float*)d_in[1];
    const float* W_ih   = (const float*)d_in[2];
    const float* b_ih   = (const float*)d_in[3];
    const float* W_fh0  = (const float*)d_in[4];
    const float* b_fh0  = (const float*)d_in[5];
    const float* W_hh   = (const float*)d_in[6];
    const float* b_hh   = (const float*)d_in[7];
    const float* Wq     = (const float*)d_in[8];
    const float* bq     = (const float*)d_in[9];
    const float* Wk     = (const float*)d_in[10];
    // d_in[11] = bk: cancels inside the 2-way softmax, unused.
    const float* Wv     = (const float*)d_in[12];
    const float* bv     = (const float*)d_in[13];
    float* outp = (float*)d_out;

    char* ws = (char*)d_ws;
    size_t off = 0;
    auto alloc = [&](size_t bytes) -> void* {
        void* p = ws + off;
        off += (bytes + 255) & ~(size_t)255;
        return p;
    };
    // Xbf is dead after gemm_lds; Vbf (same size, 64 MiB) reuses its region.
    unsigned short* Xbf  = (unsigned short*)alloc((size_t)BT_ * DIN_ * 2);
    unsigned short* Vbf  = Xbf;
    unsigned short* Abf  = (unsigned short*)alloc((size_t)BT_ * DIN_ * 2);
    unsigned short* Wpre = (unsigned short*)alloc((size_t)NPRE_ * DIN_ * 2);
    float*          Cpre = (float*)alloc((size_t)BT_ * NPRE_ * 4);
    unsigned short* Apk  = (unsigned short*)alloc((size_t)BT_ * NV_ * 2);
    unsigned short* Wcat = (unsigned short*)alloc((size_t)NCAT_ * H_ * 2);
    unsigned short* Wvbf = (unsigned short*)alloc((size_t)H_ * H_ * 2);
    float* bpre = (float*)alloc((size_t)NPRE_ * 4);
    float* bcat = (float*)alloc((size_t)NCAT_ * 4);
    float* comb = (float*)alloc((size_t)B_ * NCAT_ * 4);
    unsigned short* hxbf = (unsigned short*)alloc((size_t)B_ * H_ * 2);

    hipMemsetAsync(hxbf, 0, (size_t)B_ * H_ * 2, stream);

    auto cast = [&](const float* s, unsigned short* d, size_t n) {
        int n4 = (int)(n / 4);
        cast4_kernel<<<(n4 + 255) / 256, 256, 0, stream>>>(s, d, n4);
    };
    cast(input_feats, Xbf, (size_t)BT_ * DIN_);
    cast(aux0, Abf, (size_t)BT_ * DIN_);
    cast(W_ih, Wpre, (size_t)1536 * DIN_);
    cast(W_fh0, Wpre + (size_t)1536 * DIN_, (size_t)1024 * DIN_);
    cast(W_hh, Wcat, (size_t)1536 * H_);
    cast(Wv, Wvbf, (size_t)H_ * H_);

    hipMemcpyAsync(bpre, b_ih, 1536 * 4, hipMemcpyDeviceToDevice, stream);
    hipMemcpyAsync(bpre + 1536, b_fh0, 1024 * 4, hipMemcpyDeviceToDevice, stream);
    hipMemcpyAsync(bcat, b_hh, 1536 * 4, hipMemcpyDeviceToDevice, stream);

    wqk_kernel<<<dim3(32, 32), 256, 0, stream>>>(Wk, Wq, Wcat + (size_t)1536 * H_);
    bqk_kernel<<<8, 64, 0, stream>>>(Wk, bq, bcat + 1536);

    // Precompute: Cpre[b*T+t, :] = [gi(i_r,i_i,i_n) | gf(t1,t2)] (+ packed bf16 mirror Apk)
    gemm_lds<<<dim3(NPRE_ / 128, BT_ / 128), 256, 0, stream>>>(
        Xbf, Abf, 1536, Wpre, bpre, Cpre, Apk, NPRE_, DIN_);

    // Precompute V = [Wv*t1 | Wv*ir | Wv*t2 | Wv*ii] + bv  (Xbf region reused for Vbf)
    gemm_v<<<dim3(NV_ / 128, BT_ / 128), 256, 0, stream>>>(Apk, Wvbf, bv, Vbf);

    // Entire recurrence in ONE persistent cooperative kernel (128 launches -> 1).
    {
        void* cargs[] = {(void*)&hxbf, (void*)&Wcat, (void*)&bcat, (void*)&comb,
                         (void*)&Cpre, (void*)&Vbf, (void*)&outp};
        hipLaunchCooperativeKernel((const void*)loop_kernel, dim3(256), dim3(256),
                                   cargs, 0, stream);
    }
}

// Round 7
// 3019.412 us; speedup vs baseline: 1.7307x; 1.7307x over previous
//
#include <hip/hip_runtime.h>
#include <hip/hip_bf16.h>
#include <cstdint>
#include <cstddef>

// Problem dims
#define B_    256
#define T_    64
#define H_    512
#define DIN_  2048
#define BT_   (B_ * T_)     // 16384
#define NPRE_ 2560          // [i_r, i_i, i_n, t1, t2] columns
#define NCAT_ 2048          // [h_r, h_i, h_n, q~] columns
#define NV_   2048          // [Vt1|Vir|Vt2|Vii] columns

typedef __attribute__((ext_vector_type(8))) __bf16 bf16x8;
typedef __attribute__((ext_vector_type(8))) unsigned short u16x8;
typedef __attribute__((ext_vector_type(4))) float  f32x4;

__device__ __forceinline__ float bf2f(unsigned short u) {
    union { unsigned int i; float f; } v; v.i = ((unsigned int)u) << 16; return v.f;
}
__device__ __forceinline__ unsigned short f2bf(float f) {
    union { float f; unsigned int i; } v; v.f = f;
    unsigned int x = v.i;
    return (unsigned short)((x + 0x7fffu + ((x >> 16) & 1u)) >> 16);
}

// async global->LDS, 16B per lane (wave-uniform base + lane*16 dest).
__device__ __forceinline__ void gload_lds16(const unsigned short* g, unsigned short* l) {
    __builtin_amdgcn_global_load_lds(
        (const __attribute__((address_space(1))) void*)g,
        (__attribute__((address_space(3))) void*)l, 16, 0, 0);
}

// ---------------- cast fp32 -> bf16, 4 elems/thread ----------------
__global__ void cast4_kernel(const float* __restrict__ src,
                             unsigned short* __restrict__ dst, int n4) {
    int i = blockIdx.x * blockDim.x + threadIdx.x;
    if (i >= n4) return;
    const float4 v = ((const float4*)src)[i];
    ushort4 o;
    o.x = f2bf(v.x); o.y = f2bf(v.y); o.z = f2bf(v.z); o.w = f2bf(v.w);
    ((ushort4*)dst)[i] = o;
}

// ---------------- Wqk = Wk^T @ Wq (fp32 in, bf16 out) ----------------
__global__ __launch_bounds__(256)
void wqk_kernel(const float* __restrict__ Wk, const float* __restrict__ Wq,
                unsigned short* __restrict__ Wout) {
    __shared__ float sk[16][17], sq[16][17];
    const int tid = threadIdx.x;
    const int tx = tid & 15, ty = tid >> 4;
    const int j0 = blockIdx.y * 16, h0 = blockIdx.x * 16;
    float acc = 0.f;
    for (int o0 = 0; o0 < 512; o0 += 16) {
        sk[ty][tx] = Wk[(o0 + ty) * 512 + j0 + tx];
        sq[ty][tx] = Wq[(o0 + ty) * 512 + h0 + tx];
        __syncthreads();
        #pragma unroll
        for (int oo = 0; oo < 16; oo++)
            acc = fmaf(sk[oo][ty], sq[oo][tx], acc);
        __syncthreads();
    }
    Wout[(size_t)(j0 + ty) * 512 + h0 + tx] = f2bf(acc);
}

// bqk[j] = sum_o Wk[o,j] * bq[o]
__global__ void bqk_kernel(const float* __restrict__ Wk, const float* __restrict__ bq,
                           float* __restrict__ bout) {
    int j = blockIdx.x * 64 + threadIdx.x;
    float acc = 0.f;
    for (int o = 0; o < 512; o++)
        acc = fmaf(Wk[o * 512 + j], bq[o], acc);
    bout[j] = acc;
}

// ---------------- bf16 GEMM (m97 LDS-staged) + packed Apk mirror ----------------
__global__ __launch_bounds__(256)
void gemm_lds(const unsigned short* __restrict__ A0,
              const unsigned short* __restrict__ A1, int nsplit,
              const unsigned short* __restrict__ W,
              const float* __restrict__ bias,
              float* __restrict__ C,
              unsigned short* __restrict__ Apk, int N, int K) {
    __shared__ unsigned short sA[128 * 32];
    __shared__ unsigned short sB[128 * 32];
    const int n0 = blockIdx.x * 128;
    const int m0 = blockIdx.y * 128;
    const unsigned short* A = (n0 < nsplit) ? A0 : A1;
    const int tid = threadIdx.x;
    const int wave = tid >> 6, lane = tid & 63;
    const int wm = (wave >> 1) * 64, wn = (wave & 1) * 64;
    const int row16 = lane & 15;
    const int kq = (lane >> 4) * 8;

    f32x4 acc[4][4];
    #pragma unroll
    for (int i = 0; i < 4; i++)
        #pragma unroll
        for (int j = 0; j < 4; j++) {
            acc[i][j].x = 0.f; acc[i][j].y = 0.f; acc[i][j].z = 0.f; acc[i][j].w = 0.f;
        }

    const int srow = tid >> 2;
    const int scol = (tid & 3) * 8;
    const unsigned short* gA0 = A + (size_t)(m0 + srow) * K + scol;
    const unsigned short* gA1 = A + (size_t)(m0 + 64 + srow) * K + scol;
    const unsigned short* gB0 = W + (size_t)(n0 + srow) * K + scol;
    const unsigned short* gB1 = W + (size_t)(n0 + 64 + srow) * K + scol;
    unsigned short* dA0 = sA + tid * 8;
    unsigned short* dA1 = sA + 2048 + tid * 8;
    unsigned short* dB0 = sB + tid * 8;
    unsigned short* dB1 = sB + 2048 + tid * 8;

    for (int k = 0; k < K; k += 32) {
        gload_lds16(gA0 + k, dA0);
        gload_lds16(gA1 + k, dA1);
        gload_lds16(gB0 + k, dB0);
        gload_lds16(gB1 + k, dB1);
        __syncthreads();
        bf16x8 a[4], b[4];
        #pragma unroll
        for (int i = 0; i < 4; i++)
            a[i] = *(const bf16x8*)(const void*)(sA + (wm + i * 16 + row16) * 32 + kq);
        #pragma unroll
        for (int j = 0; j < 4; j++)
            b[j] = *(const bf16x8*)(const void*)(sB + (wn + j * 16 + row16) * 32 + kq);
        #pragma unroll
        for (int i = 0; i < 4; i++)
            #pragma unroll
            for (int j = 0; j < 4; j++)
                acc[i][j] = __builtin_amdgcn_mfma_f32_16x16x32_bf16(a[i], b[j], acc[i][j], 0, 0, 0);
        __syncthreads();
    }

    int pbase = -1;
    if (n0 >= 1536 && n0 < 2048)      pbase = n0 - 1536;  // t1 -> [0,512)
    else if (n0 < 512)                pbase = n0 + 512;   // i_r -> [512,1024)
    else if (n0 >= 2048)              pbase = n0 - 1024;  // t2 -> [1024,1536)
    else if (n0 >= 512 && n0 < 1024)  pbase = n0 + 1024;  // i_i -> [1536,2048)

    const int col = lane & 15;
    const int rbase = (lane >> 4) * 4;
    #pragma unroll
    for (int i = 0; i < 4; i++) {
        #pragma unroll
        for (int j = 0; j < 4; j++) {
            const int nloc = wn + j * 16 + col;
            const int n = n0 + nloc;
            const float bb = bias[n];
            #pragma unroll
            for (int r = 0; r < 4; r++) {
                const int m = m0 + wm + i * 16 + rbase + r;
                const float val = acc[i][j][r] + bb;
                C[(size_t)m * N + n] = val;
                if (pbase >= 0)
                    Apk[(size_t)m * NV_ + pbase + nloc] = f2bf(val);
            }
        }
    }
}

// ---------------- V pre-GEMM: Vbf = [Wv*t1|Wv*ir|Wv*t2|Wv*ii] + bv ----------------
__global__ __launch_bounds__(256)
void gemm_v(const unsigned short* __restrict__ Apk,
            const unsigned short* __restrict__ Wvbf,
            const float* __restrict__ bv,
            unsigned short* __restrict__ Vbf) {
    __shared__ unsigned short sA[128 * 32];
    __shared__ unsigned short sB[128 * 32];
    const int n0 = blockIdx.x * 128;
    const int m0 = blockIdx.y * 128;
    const int aoff = n0 & ~511;
    const int nb0 = n0 & 511;
    const int tid = threadIdx.x;
    const int wave = tid >> 6, lane = tid & 63;
    const int wm = (wave >> 1) * 64, wn = (wave & 1) * 64;
    const int row16 = lane & 15;
    const int kq = (lane >> 4) * 8;

    f32x4 acc[4][4];
    #pragma unroll
    for (int i = 0; i < 4; i++)
        #pragma unroll
        for (int j = 0; j < 4; j++) {
            acc[i][j].x = 0.f; acc[i][j].y = 0.f; acc[i][j].z = 0.f; acc[i][j].w = 0.f;
        }

    const int srow = tid >> 2;
    const int scol = (tid & 3) * 8;
    const unsigned short* gA0 = Apk + (size_t)(m0 + srow) * NV_ + aoff + scol;
    const unsigned short* gA1 = Apk + (size_t)(m0 + 64 + srow) * NV_ + aoff + scol;
    const unsigned short* gB0 = Wvbf + (size_t)(nb0 + srow) * 512 + scol;
    const unsigned short* gB1 = Wvbf + (size_t)(nb0 + 64 + srow) * 512 + scol;
    unsigned short* dA0 = sA + tid * 8;
    unsigned short* dA1 = sA + 2048 + tid * 8;
    unsigned short* dB0 = sB + tid * 8;
    unsigned short* dB1 = sB + 2048 + tid * 8;

    for (int k = 0; k < 512; k += 32) {
        gload_lds16(gA0 + k, dA0);
        gload_lds16(gA1 + k, dA1);
        gload_lds16(gB0 + k, dB0);
        gload_lds16(gB1 + k, dB1);
        __syncthreads();
        bf16x8 a[4], b[4];
        #pragma unroll
        for (int i = 0; i < 4; i++)
            a[i] = *(const bf16x8*)(const void*)(sA + (wm + i * 16 + row16) * 32 + kq);
        #pragma unroll
        for (int j = 0; j < 4; j++)
            b[j] = *(const bf16x8*)(const void*)(sB + (wn + j * 16 + row16) * 32 + kq);
        #pragma unroll
        for (int i = 0; i < 4; i++)
            #pragma unroll
            for (int j = 0; j < 4; j++)
                acc[i][j] = __builtin_amdgcn_mfma_f32_16x16x32_bf16(a[i], b[j], acc[i][j], 0, 0, 0);
        __syncthreads();
    }

    const int col = lane & 15;
    const int rbase = (lane >> 4) * 4;
    #pragma unroll
    for (int i = 0; i < 4; i++) {
        #pragma unroll
        for (int j = 0; j < 4; j++) {
            const int nloc = wn + j * 16 + col;
            const float bb = bv[nb0 + nloc];
            #pragma unroll
            for (int r = 0; r < 4; r++) {
                const int m = m0 + wm + i * 16 + rbase + r;
                Vbf[(size_t)m * NV_ + n0 + nloc] = f2bf(acc[i][j][r] + bb);
            }
        }
    }
}

// ---------------- custom per-group barrier (sense-reversal, tight spin) ----------------
// Same fence semantics as cg::grid.sync (release fence -> arrive -> acquire fence),
// but: (a) only 8 arrivals per barrier, (b) s_sleep(1) polls instead of long backoff.
__device__ __forceinline__ void group_barrier(unsigned* cnt, unsigned* gen, unsigned nb) {
    __syncthreads();   // all waves' stores drained (compiler emits vmcnt(0) before s_barrier)
    if (threadIdx.x == 0) {
        __threadfence();  // release: write back this XCD's dirty L2 lines
        unsigned g = __hip_atomic_load(gen, __ATOMIC_RELAXED, __HIP_MEMORY_SCOPE_AGENT);
        unsigned a = __hip_atomic_fetch_add(cnt, 1u, __ATOMIC_ACQ_REL, __HIP_MEMORY_SCOPE_AGENT);
        if (a == nb - 1u) {
            __hip_atomic_store(cnt, 0u, __ATOMIC_RELAXED, __HIP_MEMORY_SCOPE_AGENT);
            __hip_atomic_store(gen, g + 1u, __ATOMIC_RELEASE, __HIP_MEMORY_SCOPE_AGENT);
        } else {
            while (__hip_atomic_load(gen, __ATOMIC_ACQUIRE, __HIP_MEMORY_SCOPE_AGENT) == g) {
                __builtin_amdgcn_s_sleep(1);
            }
        }
        __threadfence();  // acquire: invalidate stale L1/L2 before reading peers' data
    }
    __syncthreads();
}

// ---------------- persistent recurrence: 8 independent groups of 8 blocks ----------------
// Group g owns batch rows [g*32, g*32+32). Block gi in group: phase-1 computes
// comb[g rows, gi*256 .. gi*256+256) = hxbf @ Wcat^T + bcat (wave tile 16x128,
// direct loads, 8 MFMA acc). Phase-2: wave w handles row b2 = g*32+gi*4+w fully
// wave-local (shuffle-reduce dots; hx carried in 8 regs/lane). Two group
// barriers per step; groups never interact (disjoint comb/hxbf/out rows).
__global__ __launch_bounds__(256)
void rec_kernel(unsigned short* __restrict__ hxbf,      // [256,512] bf16, init 0
                const unsigned short* __restrict__ Wcat,// [2048,512] bf16
                const float* __restrict__ bcat,         // [2048]
                float* __restrict__ comb,               // [256,2048] fp32 scratch
                const float* __restrict__ Cpre,         // [16384,2560]
                const unsigned short* __restrict__ Vbf, // [16384,2048]
                float* __restrict__ out,
                unsigned* __restrict__ bar_cnt,         // [8]
                unsigned* __restrict__ bar_gen) {       // [8]
    const int bid = blockIdx.x;       // 0..63
    const int g  = bid >> 3;          // group 0..7
    const int gi = bid & 7;           // block in group 0..7
    const int tid = threadIdx.x;
    const int wave = tid >> 6, lane = tid & 63;
    unsigned* cnt = bar_cnt + g;
    unsigned* gen = bar_gen + g;

    // phase-1 geometry: rows [g*32,g*32+32), cols [gi*256,gi*256+256)
    const int m0 = g * 32;
    const int n0 = gi * 256;
    const int wr = wave & 1, wc = wave >> 1;
    const int row16 = lane & 15, kq = (lane >> 4) * 8;
    const int col = lane & 15, rbase = (lane >> 4) * 4;
    const unsigned short* abase = hxbf + (size_t)(m0 + wr * 16 + row16) * H_ + kq;
    const unsigned short* bbase = Wcat + (size_t)(n0 + wc * 128 + row16) * H_ + kq;
    float bb[8];
    #pragma unroll
    for (int j = 0; j < 8; j++) bb[j] = bcat[n0 + wc * 128 + j * 16 + col];

    // phase-2 state: wave -> row b2, lane -> h in [hb, hb+8)
    const int b2 = g * 32 + gi * 4 + wave;
    const int hb = lane * 8;
    float hy[8];
    #pragma unroll
    for (int i = 0; i < 8; i++) hy[i] = 0.f;
    const float scale = 0.04419417382415922f; // 1/sqrt(512)

    for (int t = 0; t < T_; t++) {
        // ---- phase 1: comb tile (32 x 256)
        f32x4 acc[8];
        #pragma unroll
        for (int j = 0; j < 8; j++) { acc[j].x = 0.f; acc[j].y = 0.f; acc[j].z = 0.f; acc[j].w = 0.f; }
        #pragma unroll 2
        for (int k = 0; k < H_; k += 32) {
            const bf16x8 av = *(const bf16x8*)(const void*)(abase + k);
            #pragma unroll
            for (int j = 0; j < 8; j++) {
                const bf16x8 bv8 = *(const bf16x8*)(const void*)(bbase + (size_t)j * 16 * H_ + k);
                acc[j] = __builtin_amdgcn_mfma_f32_16x16x32_bf16(av, bv8, acc[j], 0, 0, 0);
            }
        }
        {
            const int m = m0 + wr * 16 + rbase;
            #pragma unroll
            for (int j = 0; j < 8; j++) {
                const int n = n0 + wc * 128 + j * 16 + col;
                #pragma unroll
                for (int r = 0; r < 4; r++)
                    comb[(size_t)(m + r) * NCAT_ + n] = acc[j][r] + bb[j];
            }
        }
        group_barrier(cnt, gen, 8u);   // comb(group rows) complete & visible

        // ---- phase 2: attention + gates, wave-local on row b2
        {
            const float* combRow = comb + (size_t)b2 * NCAT_;
            const float* pre = Cpre + (size_t)(b2 * T_ + t) * NPRE_;
            const unsigned short* vrow = Vbf + (size_t)(b2 * T_ + t) * NV_;

            const float4 qa  = *(const float4*)&combRow[1536 + hb];
            const float4 qb  = *(const float4*)&combRow[1540 + hb];
            const float4 t1a = *(const float4*)&pre[1536 + hb];
            const float4 t1b = *(const float4*)&pre[1540 + hb];
            const float4 ira = *(const float4*)&pre[hb];
            const float4 irb = *(const float4*)&pre[hb + 4];
            const float4 t2a = *(const float4*)&pre[2048 + hb];
            const float4 t2b = *(const float4*)&pre[2052 + hb];
            const float4 iia = *(const float4*)&pre[512 + hb];
            const float4 iib = *(const float4*)&pre[516 + hb];

            float pr0 = qa.x*t1a.x + qa.y*t1a.y + qa.z*t1a.z + qa.w*t1a.w
                      + qb.x*t1b.x + qb.y*t1b.y + qb.z*t1b.z + qb.w*t1b.w;
            float pr1 = qa.x*ira.x + qa.y*ira.y + qa.z*ira.z + qa.w*ira.w
                      + qb.x*irb.x + qb.y*irb.y + qb.z*irb.z + qb.w*irb.w;
            float pi0 = qa.x*t2a.x + qa.y*t2a.y + qa.z*t2a.z + qa.w*t2a.w
                      + qb.x*t2b.x + qb.y*t2b.y + qb.z*t2b.z + qb.w*t2b.w;
            float pi1 = qa.x*iia.x + qa.y*iia.y + qa.z*iia.z + qa.w*iia.w
                      + qb.x*iib.x + qb.y*iib.y + qb.z*iib.z + qb.w*iib.w;
            #pragma unroll
            for (int mm = 32; mm >= 1; mm >>= 1) {
                pr0 += __shfl_xor(pr0, mm);
                pr1 += __shfl_xor(pr1, mm);
                pi0 += __shfl_xor(pi0, mm);
                pi1 += __shfl_xor(pi1, mm);
            }
            const float prob_r0 = 1.f / (1.f + expf((pr1 - pr0) * scale));
            const float prob_i0 = 1.f / (1.f + expf((pi1 - pi0) * scale));

            const u16x8 vt1 = *(const u16x8*)(const void*)&vrow[hb];
            const u16x8 vir = *(const u16x8*)(const void*)&vrow[512 + hb];
            const u16x8 vt2 = *(const u16x8*)(const void*)&vrow[1024 + hb];
            const u16x8 vii = *(const u16x8*)(const void*)&vrow[1536 + hb];
            const float4 hra = *(const float4*)&combRow[hb];
            const float4 hrb = *(const float4*)&combRow[hb + 4];
            const float4 hia = *(const float4*)&combRow[512 + hb];
            const float4 hib = *(const float4*)&combRow[516 + hb];
            const float4 hna = *(const float4*)&combRow[1024 + hb];
            const float4 hnb = *(const float4*)&combRow[1028 + hb];
            const float4 ina = *(const float4*)&pre[1024 + hb];
            const float4 inb = *(const float4*)&pre[1028 + hb];
            const float hr[8] = {hra.x, hra.y, hra.z, hra.w, hrb.x, hrb.y, hrb.z, hrb.w};
            const float hi[8] = {hia.x, hia.y, hia.z, hia.w, hib.x, hib.y, hib.z, hib.w};
            const float hn[8] = {hna.x, hna.y, hna.z, hna.w, hnb.x, hnb.y, hnb.z, hnb.w};
            const float i8[8] = {ina.x, ina.y, ina.z, ina.w, inb.x, inb.y, inb.z, inb.w};

            u16x8 hout;
            #pragma unroll
            for (int i = 0; i < 8; i++) {
                const float cr = prob_r0 * bf2f(vt1[i]) + (1.f - prob_r0) * bf2f(vir[i]);
                const float ci = prob_i0 * bf2f(vt2[i]) + (1.f - prob_i0) * bf2f(vii[i]);
                const float rg = 1.f / (1.f + expf(-(cr + hr[i])));
                const float ig = 1.f / (1.f + expf(-(ci + hi[i])));
                const float ng = tanhf(fmaf(rg, hn[i], i8[i]));
                hy[i] = ng + ig * (hy[i] - ng);
                hout[i] = f2bf(hy[i]);
            }
            float* orow = out + (size_t)(b2 * T_ + t) * H_ + hb;
            *(float4*)&orow[0] = make_float4(hy[0], hy[1], hy[2], hy[3]);
            *(float4*)&orow[4] = make_float4(hy[4], hy[5], hy[6], hy[7]);
            *(u16x8*)(void*)&hxbf[(size_t)b2 * H_ + hb] = hout;
            if (t == T_ - 1) {
                float* frow = out + (size_t)B_ * T_ * H_ + (size_t)b2 * H_ + hb;
                *(float4*)&frow[0] = make_float4(hy[0], hy[1], hy[2], hy[3]);
                *(float4*)&frow[4] = make_float4(hy[4], hy[5], hy[6], hy[7]);
            }
        }
        group_barrier(cnt, gen, 8u);   // hxbf(group rows) complete & visible
    }
}

extern "C" void kernel_launch(void* const* d_in, const int* in_sizes, int n_in,
                              void* d_out, int out_size, void* d_ws, size_t ws_size,
                              hipStream_t stream) {
    const float* input_feats = (const float*)d_in[0];
    const float* aux0   = (const float*)d_in[1];
    const float* W_ih   = (const float*)d_in[2];
    const float* b_ih   = (const float*)d_in[3];
    const float* W_fh0  = (const float*)d_in[4];
    const float* b_fh0  = (const float*)d_in[5];
    const float* W_hh   = (const float*)d_in[6];
    const float* b_hh   = (const float*)d_in[7];
    const float* Wq     = (const float*)d_in[8];
    const float* bq     = (const float*)d_in[9];
    const float* Wk     = (const float*)d_in[10];
    // d_in[11] = bk: cancels inside the 2-way softmax, unused.
    const float* Wv     = (const float*)d_in[12];
    const float* bv     = (const float*)d_in[13];
    float* outp = (float*)d_out;

    char* ws = (char*)d_ws;
    size_t off = 0;
    auto alloc = [&](size_t bytes) -> void* {
        void* p = ws + off;
        off += (bytes + 255) & ~(size_t)255;
        return p;
    };
    // Xbf is dead after gemm_lds; Vbf (same size, 64 MiB) reuses its region.
    unsigned short* Xbf  = (unsigned short*)alloc((size_t)BT_ * DIN_ * 2);
    unsigned short* Vbf  = Xbf;
    unsigned short* Abf  = (unsigned short*)alloc((size_t)BT_ * DIN_ * 2);
    unsigned short* Wpre = (unsigned short*)alloc((size_t)NPRE_ * DIN_ * 2);
    float*          Cpre = (float*)alloc((size_t)BT_ * NPRE_ * 4);
    unsigned short* Apk  = (unsigned short*)alloc((size_t)BT_ * NV_ * 2);
    unsigned short* Wcat = (unsigned short*)alloc((size_t)NCAT_ * H_ * 2);
    unsigned short* Wvbf = (unsigned short*)alloc((size_t)H_ * H_ * 2);
    float* bpre = (float*)alloc((size_t)NPRE_ * 4);
    float* bcat = (float*)alloc((size_t)NCAT_ * 4);
    float* comb = (float*)alloc((size_t)B_ * NCAT_ * 4);
    unsigned short* hxbf = (unsigned short*)alloc((size_t)B_ * H_ * 2);
    unsigned* bar_cnt = (unsigned*)alloc(8 * 4);
    unsigned* bar_gen = (unsigned*)alloc(8 * 4);

    hipMemsetAsync(hxbf, 0, (size_t)B_ * H_ * 2, stream);
    hipMemsetAsync(bar_cnt, 0, 8 * 4, stream);
    hipMemsetAsync(bar_gen, 0, 8 * 4, stream);

    auto cast = [&](const float* s, unsigned short* d, size_t n) {
        int n4 = (int)(n / 4);
        cast4_kernel<<<(n4 + 255) / 256, 256, 0, stream>>>(s, d, n4);
    };
    cast(input_feats, Xbf, (size_t)BT_ * DIN_);
    cast(aux0, Abf, (size_t)BT_ * DIN_);
    cast(W_ih, Wpre, (size_t)1536 * DIN_);
    cast(W_fh0, Wpre + (size_t)1536 * DIN_, (size_t)1024 * DIN_);
    cast(W_hh, Wcat, (size_t)1536 * H_);
    cast(Wv, Wvbf, (size_t)H_ * H_);

    hipMemcpyAsync(bpre, b_ih, 1536 * 4, hipMemcpyDeviceToDevice, stream);
    hipMemcpyAsync(bpre + 1536, b_fh0, 1024 * 4, hipMemcpyDeviceToDevice, stream);
    hipMemcpyAsync(bcat, b_hh, 1536 * 4, hipMemcpyDeviceToDevice, stream);

    wqk_kernel<<<dim3(32, 32), 256, 0, stream>>>(Wk, Wq, Wcat + (size_t)1536 * H_);
    bqk_kernel<<<8, 64, 0, stream>>>(Wk, bq, bcat + 1536);

    // Precompute: Cpre = [gi | gf] (+ packed bf16 mirror Apk)
    gemm_lds<<<dim3(NPRE_ / 128, BT_ / 128), 256, 0, stream>>>(
        Xbf, Abf, 1536, Wpre, bpre, Cpre, Apk, NPRE_, DIN_);

    // Precompute V = [Wv*t1 | Wv*ir | Wv*t2 | Wv*ii] + bv
    gemm_v<<<dim3(NV_ / 128, BT_ / 128), 256, 0, stream>>>(Apk, Wvbf, bv, Vbf);

    // Entire recurrence: one persistent kernel, 8 independent groups of 8 blocks,
    // custom per-group barriers (cooperative launch only for residency guarantee).
    {
        void* cargs[] = {(void*)&hxbf, (void*)&Wcat, (void*)&bcat, (void*)&comb,
                         (void*)&Cpre, (void*)&Vbf, (void*)&outp,
                         (void*)&bar_cnt, (void*)&bar_gen};
        hipLaunchCooperativeKernel((const void*)rec_kernel, dim3(64), dim3(256),
                                   cargs, 0, stream);
    }
}